// Round 5
// baseline (153.096 us; speedup 1.0000x reference)
//
#include <hip/hip_runtime.h>
#include <hip/hip_bf16.h>

// ---------------------------------------------------------------------------
// ContrastiveLoss: B=8192, D=64, fp32 inputs, scalar fp32 output.
// Two kernels (graph nodes cost ~3 us each, measured R2):
//   1) norm: fused |x|^2,|t|^2,x.t butterfly per row; bf16 copies (imgB
//      pre-scaled by K1 = LOG2E/T); exact fp32 diagonal; zero rowSum/colSum/
//      ticket counter (kernel boundary publishes to kernel 2).
//   2) score: streamed MFMA pass (C init = -K1 so acc IS the exp2 arg),
//      exp2, row/col sums accumulated via device-scope atomicAdd; the block
//      drawing the LAST ticket computes the focal loss and stores out[0].
// No max pass needed: unit vectors => |s| <= 1/T; fixed shift M = 1/T keeps
// exp(s-M) in [e^-28.6, 1] (fp32-safe).
// NOTE: cooperative launch (R4) fails under this harness's graph capture —
// last-block-done + device-scope atomics is the capture-safe fusion.
// ---------------------------------------------------------------------------

#define NB 8192
#define ND 64

constexpr float INV_T = 1.0f / 0.07f;                 // 14.2857...
constexpr float LOG2E = 1.4426950408889634f;
constexpr float LN2   = 0.6931471805599453f;
constexpr float K1    = INV_T * LOG2E;                // exp2 arg scale

typedef float  floatx4 __attribute__((ext_vector_type(4)));
typedef short  bf16x8  __attribute__((ext_vector_type(8)));

// --------------------------- kernel 1: normalize ---------------------------
// One wave per row (D=64 == wave width). Also zeroes the accumulators and
// the ticket counter for kernel 2 (visibility via kernel-launch boundary).
__global__ __launch_bounds__(256)
void norm_kernel(const float* __restrict__ img, const float* __restrict__ txt,
                 __hip_bfloat16* __restrict__ imgB,
                 __hip_bfloat16* __restrict__ txtB,
                 float* __restrict__ diag,
                 float* __restrict__ rowSum,    // [8192]
                 float* __restrict__ colSum,    // [8192]
                 unsigned int* __restrict__ counter)
{
    const int tid = threadIdx.x;
    if (blockIdx.x < 32) {                       // zero accumulators
        rowSum[blockIdx.x * 256 + tid] = 0.f;
        colSum[blockIdx.x * 256 + tid] = 0.f;
        if (blockIdx.x == 0 && tid == 0) *counter = 0u;
    }
    const int lane = tid & 63;
    const int row  = blockIdx.x * 4 + (tid >> 6);
    const float x = img[row * ND + lane];
    const float t = txt[row * ND + lane];
    float sx = x * x, st = t * t, sxt = x * t;
    #pragma unroll
    for (int o = 1; o < 64; o <<= 1) {
        sx  += __shfl_xor(sx,  o, 64);
        st  += __shfl_xor(st,  o, 64);
        sxt += __shfl_xor(sxt, o, 64);
    }
    const float nx_den = fmaxf(sqrtf(sx), 1e-12f);
    const float nt_den = fmaxf(sqrtf(st), 1e-12f);
    imgB[row * ND + lane] = __float2bfloat16(x / nx_den * K1);  // A pre-scaled
    txtB[row * ND + lane] = __float2bfloat16(t / nt_den);
    if (lane == 0) diag[row] = sxt / (nx_den * nt_den) * INV_T;
}

// ------------------- kernel 2: score + last-block finish -------------------
// Wave gw: strip = gw>>5 (64 rows), chunk = gw&31 (256 cols, 16 tiles of 16).
// A-fragments (4 row-tiles) stay in registers across the tile loop; next
// tile's B-fragments software-prefetched (branchless wraparound).
// mfma_f32_16x16x32_bf16 layouts (HW-verified):
//   A: lane holds A[m=lane&15][k=(lane>>4)*8 + j], j=0..7  (8 contig bf16)
//   B: lane holds B[n=lane&15][k=(lane>>4)*8 + j]          (NT layout)
//   C/D: col = lane&15, row = (lane>>4)*4 + r
__global__ __launch_bounds__(256)
void score_kernel(const __hip_bfloat16* __restrict__ imgB,
                  const __hip_bfloat16* __restrict__ txtB,
                  const float* __restrict__ diag,
                  float* __restrict__ rowSum,    // [8192] atomic accumulators
                  float* __restrict__ colSum,    // [8192]
                  unsigned int* __restrict__ counter,
                  float* __restrict__ out)
{
    const int tid  = threadIdx.x;
    const int wid  = tid >> 6;
    const int lane = tid & 63;
    const int gw    = blockIdx.x * 4 + wid;   // 0..4095
    const int strip = gw >> 5;                // rows strip*64..+63
    const int chunk = gw & 31;                // cols chunk*256..+255
    const int m = lane & 15;
    const int q = lane >> 4;

    const bf16x8* __restrict__ A  = (const bf16x8*)imgB;  // units of 8 elems
    const bf16x8* __restrict__ Bp = (const bf16x8*)txtB;

    const int rowbase = strip * 64;
    bf16x8 a[4][2];
    #pragma unroll
    for (int it = 0; it < 4; ++it) {
        const int r = rowbase + it * 16 + m;
        a[it][0] = A[r * 8 + q];        // k = q*8 .. q*8+7
        a[it][1] = A[r * 8 + 4 + q];    // k = 32 + q*8 ..
    }

    const int colbase = chunk * 256 + m;      // this lane's t=0 column
    bf16x8 b0 = Bp[colbase * 8 + q];
    bf16x8 b1 = Bp[colbase * 8 + 4 + q];

    float rs[16];
    #pragma unroll
    for (int i = 0; i < 16; ++i) rs[i] = 0.f;

    const floatx4 NEGK = {-K1, -K1, -K1, -K1};   // bakes the -M shift in

    #pragma unroll 2
    for (int t = 0; t < 16; ++t) {
        // prefetch next tile's B (t=15 wraps: harmless, avoids branch)
        const int nn = colbase + (((t + 1) & 15) << 4);
        const bf16x8 pb0 = Bp[nn * 8 + q];
        const bf16x8 pb1 = Bp[nn * 8 + 4 + q];

        float csp[4];
        #pragma unroll
        for (int it = 0; it < 4; ++it) {
            floatx4 z   = __builtin_amdgcn_mfma_f32_16x16x32_bf16(a[it][0], b0, NEGK, 0, 0, 0);
            floatx4 acc = __builtin_amdgcn_mfma_f32_16x16x32_bf16(a[it][1], b1, z,    0, 0, 0);
            // acc == (s - M) * log2(e) already
            const float e0 = __builtin_amdgcn_exp2f(acc[0]);
            const float e1 = __builtin_amdgcn_exp2f(acc[1]);
            const float e2 = __builtin_amdgcn_exp2f(acc[2]);
            const float e3 = __builtin_amdgcn_exp2f(acc[3]);
            rs[it * 4 + 0] += e0;
            rs[it * 4 + 1] += e1;
            rs[it * 4 + 2] += e2;
            rs[it * 4 + 3] += e3;
            csp[it] = (e0 + e1) + (e2 + e3);     // depth-2 tree
        }
        float cs = (csp[0] + csp[1]) + (csp[2] + csp[3]);
        // combine the 4 quads -> col sum over all 64 rows of the strip
        cs += __shfl_xor(cs, 16, 64);
        cs += __shfl_xor(cs, 32, 64);
        if (q == 0) atomicAdd(&colSum[colbase + (t << 4)], cs);
        b0 = pb0; b1 = pb1;
    }

    // flush row sums: reduce each rs[idx] across the 16 lanes of the quad
    #pragma unroll
    for (int idx = 0; idx < 16; ++idx) {
        float v = rs[idx];
        v += __shfl_xor(v, 1, 64);
        v += __shfl_xor(v, 2, 64);
        v += __shfl_xor(v, 4, 64);
        v += __shfl_xor(v, 8, 64);
        if (m == idx)
            atomicAdd(&rowSum[rowbase + ((idx >> 2) << 4) + q * 4 + (idx & 3)], v);
    }

    // ---------------- last-block-done: finish phase ------------------------
    __shared__ unsigned int s_ticket;
    __threadfence();                      // drain this block's atomics
    __syncthreads();
    if (tid == 0) s_ticket = atomicAdd(counter, 1u);
    __syncthreads();
    if (s_ticket != (unsigned)(gridDim.x - 1)) return;   // not last: done

    // Last block: all rowSum/colSum atomics from every block have completed
    // (each block fenced before taking its ticket). Read them back with
    // atomic-loads (atomicAdd(p, 0) -> old value) to stay on the coherent
    // path regardless of per-XCD L2 state. diag is safe (prior kernel).
    float contrib = 0.f;
    for (int i = tid; i < NB; i += 256) {
        const float rowS = atomicAdd(&rowSum[i], 0.f);
        const float colS = atomicAdd(&colSum[i], 0.f);
        const float d     = diag[i];
        const float lse_r = INV_T + __builtin_amdgcn_logf(rowS) * LN2;
        const float lse_c = INV_T + __builtin_amdgcn_logf(colS) * LN2;
        const float lpr = d - lse_r;
        const float lpc = d - lse_c;
        const float p   = __builtin_amdgcn_exp2f(lpr * LOG2E);
        const float om  = 1.f - p;
        contrib += om * om * (-lpr - lpc);
    }
    contrib *= (0.5f / (float)NB);
    #pragma unroll
    for (int o = 1; o < 64; o <<= 1) contrib += __shfl_xor(contrib, o, 64);
    __shared__ float red[4];
    if (lane == 0) red[wid] = contrib;
    __syncthreads();
    if (tid == 0) out[0] = (red[0] + red[1]) + (red[2] + red[3]);
}

// ---------------------------------------------------------------------------
extern "C" void kernel_launch(void* const* d_in, const int* in_sizes, int n_in,
                              void* d_out, int out_size, void* d_ws, size_t ws_size,
                              hipStream_t stream)
{
    const float* img = (const float*)d_in[0];
    const float* txt = (const float*)d_in[1];

    char* ws = (char*)d_ws;
    __hip_bfloat16* imgB = (__hip_bfloat16*)(ws);                  // 1 MB
    __hip_bfloat16* txtB = (__hip_bfloat16*)(ws + (1u << 20));     // 1 MB
    float* diag   = (float*)(ws + (2u << 20));                     // 32 KB
    float* rowSum = (float*)(ws + (2u << 20) + (1u << 16));        // 32 KB
    float* colSum = (float*)(ws + (2u << 20) + (2u << 16));        // 32 KB
    unsigned int* counter = (unsigned int*)(ws + (2u << 20) + (3u << 16));

    norm_kernel<<<NB / 4, 256, 0, stream>>>(img, txt, imgB, txtB, diag,
                                            rowSum, colSum, counter);
    score_kernel<<<1024, 256, 0, stream>>>(imgB, txtB, diag, rowSum, colSum,
                                           counter, (float*)d_out);
}

// Round 6
// 106.050 us; speedup vs baseline: 1.4436x; 1.4436x over previous
//
#include <hip/hip_runtime.h>
#include <hip/hip_bf16.h>

// ---------------------------------------------------------------------------
// ContrastiveLoss: B=8192, D=64, fp32 inputs, scalar fp32 output.
// Three kernels (R5 lesson: contended fp32 atomics + ticket fusion cost +55us;
// unique-writer partial stores with kernel-boundary coherence are the fast path):
//   1) norm: fused |x|^2,|t|^2,x.t butterfly per row; bf16 copies (imgB
//      pre-scaled by K1 = LOG2E/T); exact fp32 diagonal; zero d_out.
//   2) score: streamed MFMA pass (C init = -K1 so acc IS the exp2 arg), exp2,
//      row/col partials, unique-writer stores. R6: 2048 blocks (was 1024) --
//      8 blocks/CU, 32 waves/CU (VGPR=64 permits) to hide the L2/IF$ and
//      MFMA->exp2 latency the R5 counters exposed (all pipes <10% busy).
//   3) finish: reduce 64 row-partials + 128 col-partials -> logsumexp ->
//      focal loss -> one atomicAdd per block (32 total).
// No max pass needed: unit vectors => |s| <= 1/T; fixed shift M = 1/T keeps
// exp(s-M) in [e^-28.6, 1] (fp32-safe).
// ---------------------------------------------------------------------------

#define NB 8192
#define ND 64

constexpr float INV_T = 1.0f / 0.07f;                 // 14.2857...
constexpr float LOG2E = 1.4426950408889634f;
constexpr float LN2   = 0.6931471805599453f;
constexpr float K1    = INV_T * LOG2E;                // exp2 arg scale

typedef float  floatx4 __attribute__((ext_vector_type(4)));
typedef short  bf16x8  __attribute__((ext_vector_type(8)));

// --------------------------- kernel 1: normalize ---------------------------
// One wave per row (D=64 == wave width). Single fused butterfly reduces
// |x|^2, |t|^2, x.t together. imgB gets the K1-prescaled bf16 copy (A side),
// txtB the plain normalized bf16 (B side). Exact fp32 diagonal to diag.
// Also zeroes d_out (kernel boundary orders it before finish's atomicAdd).
__global__ __launch_bounds__(256)
void norm_kernel(const float* __restrict__ img, const float* __restrict__ txt,
                 __hip_bfloat16* __restrict__ imgB,
                 __hip_bfloat16* __restrict__ txtB,
                 float* __restrict__ diag,
                 float* __restrict__ out)
{
    if (blockIdx.x == 0 && threadIdx.x == 0) out[0] = 0.f;
    const int lane = threadIdx.x & 63;
    const int row  = blockIdx.x * 4 + (threadIdx.x >> 6);
    const float x = img[row * ND + lane];
    const float t = txt[row * ND + lane];
    float sx = x * x, st = t * t, sxt = x * t;
    #pragma unroll
    for (int o = 1; o < 64; o <<= 1) {
        sx  += __shfl_xor(sx,  o, 64);
        st  += __shfl_xor(st,  o, 64);
        sxt += __shfl_xor(sxt, o, 64);
    }
    const float nx_den = fmaxf(sqrtf(sx), 1e-12f);
    const float nt_den = fmaxf(sqrtf(st), 1e-12f);
    imgB[row * ND + lane] = __float2bfloat16(x / nx_den * K1);  // A pre-scaled
    txtB[row * ND + lane] = __float2bfloat16(t / nt_den);
    if (lane == 0) diag[row] = sxt / (nx_den * nt_den) * INV_T;
}

// ----------------------- kernel 2: streamed score pass ---------------------
// 2048 blocks x 4 waves = 8192 waves = 128 strips (64 rows) x 64 chunks
// (128 cols = 8 tiles of 16). A-fragments (4 row-tiles) live in registers
// across the tile loop; next tile's B software-prefetched (branchless wrap).
// mfma_f32_16x16x32_bf16 layouts (HW-verified):
//   A: lane holds A[m=lane&15][k=(lane>>4)*8 + j], j=0..7  (8 contig bf16)
//   B: lane holds B[n=lane&15][k=(lane>>4)*8 + j]          (NT layout)
//   C/D: col = lane&15, row = (lane>>4)*4 + r
__global__ __launch_bounds__(256)
void score_kernel(const __hip_bfloat16* __restrict__ imgB,
                  const __hip_bfloat16* __restrict__ txtB,
                  float* __restrict__ rowPart,   // [64][8192]
                  float* __restrict__ colPart)   // [128][8192]
{
    const int wid   = threadIdx.x >> 6;
    const int lane  = threadIdx.x & 63;
    const int gw    = blockIdx.x * 4 + wid;   // 0..8191
    const int strip = gw >> 6;                // rows strip*64..+63
    const int chunk = gw & 63;                // cols chunk*128..+127
    const int m = lane & 15;
    const int q = lane >> 4;

    const bf16x8* __restrict__ A  = (const bf16x8*)imgB;  // units of 8 elems
    const bf16x8* __restrict__ Bp = (const bf16x8*)txtB;

    const int rowbase = strip * 64;
    bf16x8 a[4][2];
    #pragma unroll
    for (int it = 0; it < 4; ++it) {
        const int r = rowbase + it * 16 + m;
        a[it][0] = A[r * 8 + q];        // k = q*8 .. q*8+7
        a[it][1] = A[r * 8 + 4 + q];    // k = 32 + q*8 ..
    }

    const int colbase = chunk * 128 + m;      // this lane's t=0 column
    bf16x8 b0 = Bp[colbase * 8 + q];
    bf16x8 b1 = Bp[colbase * 8 + 4 + q];

    float rs[16];
    #pragma unroll
    for (int i = 0; i < 16; ++i) rs[i] = 0.f;

    const floatx4 NEGK = {-K1, -K1, -K1, -K1};   // bakes the -M shift in

    #pragma unroll 2
    for (int t = 0; t < 8; ++t) {
        // prefetch next tile's B (t=7 wraps to t=0: harmless, avoids branch)
        const int nn = colbase + (((t + 1) & 7) << 4);
        const bf16x8 pb0 = Bp[nn * 8 + q];
        const bf16x8 pb1 = Bp[nn * 8 + 4 + q];

        float csp[4];
        #pragma unroll
        for (int it = 0; it < 4; ++it) {
            floatx4 z   = __builtin_amdgcn_mfma_f32_16x16x32_bf16(a[it][0], b0, NEGK, 0, 0, 0);
            floatx4 acc = __builtin_amdgcn_mfma_f32_16x16x32_bf16(a[it][1], b1, z,    0, 0, 0);
            // acc == (s - M) * log2(e) already
            const float e0 = __builtin_amdgcn_exp2f(acc[0]);
            const float e1 = __builtin_amdgcn_exp2f(acc[1]);
            const float e2 = __builtin_amdgcn_exp2f(acc[2]);
            const float e3 = __builtin_amdgcn_exp2f(acc[3]);
            rs[it * 4 + 0] += e0;
            rs[it * 4 + 1] += e1;
            rs[it * 4 + 2] += e2;
            rs[it * 4 + 3] += e3;
            csp[it] = (e0 + e1) + (e2 + e3);     // depth-2 tree
        }
        float cs = (csp[0] + csp[1]) + (csp[2] + csp[3]);
        // combine the 4 quads -> col sum over all 64 rows of the strip
        cs += __shfl_xor(cs, 16, 64);
        cs += __shfl_xor(cs, 32, 64);
        if (q == 0) colPart[strip * NB + colbase + (t << 4)] = cs;  // unique writer
        b0 = pb0; b1 = pb1;
    }

    // flush row sums: reduce each rs[idx] across the 16 lanes of the quad
    #pragma unroll
    for (int idx = 0; idx < 16; ++idx) {
        float v = rs[idx];
        v += __shfl_xor(v, 1, 64);
        v += __shfl_xor(v, 2, 64);
        v += __shfl_xor(v, 4, 64);
        v += __shfl_xor(v, 8, 64);
        if (m == idx) {
            const int it = idx >> 2, r = idx & 3;
            rowPart[chunk * NB + rowbase + it * 16 + q * 4 + r] = v;  // unique writer
        }
    }
}

// --------------------------- kernel 3: finish ------------------------------
__global__ __launch_bounds__(256)
void finish_kernel(const float* __restrict__ rowPart,
                   const float* __restrict__ colPart,
                   const float* __restrict__ diag,
                   float* __restrict__ out)
{
    const int i = blockIdx.x * 256 + threadIdx.x;   // 0..8191
    float rowS = 0.f, colS = 0.f;
    #pragma unroll 4
    for (int c = 0; c < 64; ++c)  rowS += rowPart[c * NB + i];
    #pragma unroll 4
    for (int s = 0; s < 128; ++s) colS += colPart[s * NB + i];
    const float d     = diag[i];
    const float lse_r = INV_T + __builtin_amdgcn_logf(rowS) * LN2;
    const float lse_c = INV_T + __builtin_amdgcn_logf(colS) * LN2;
    const float lpr = d - lse_r;
    const float lpc = d - lse_c;
    const float p   = __builtin_amdgcn_exp2f(lpr * LOG2E);
    const float om  = 1.f - p;
    float contrib = om * om * (-lpr - lpc) * (0.5f / (float)NB);

    #pragma unroll
    for (int o = 1; o < 64; o <<= 1) contrib += __shfl_xor(contrib, o, 64);
    __shared__ float red[4];
    if ((threadIdx.x & 63) == 0) red[threadIdx.x >> 6] = contrib;
    __syncthreads();
    if (threadIdx.x == 0)
        atomicAdd(out, red[0] + red[1] + red[2] + red[3]);
}

// ---------------------------------------------------------------------------
extern "C" void kernel_launch(void* const* d_in, const int* in_sizes, int n_in,
                              void* d_out, int out_size, void* d_ws, size_t ws_size,
                              hipStream_t stream)
{
    const float* img = (const float*)d_in[0];
    const float* txt = (const float*)d_in[1];

    char* ws = (char*)d_ws;
    __hip_bfloat16* imgB = (__hip_bfloat16*)(ws);                        // 1 MB
    __hip_bfloat16* txtB = (__hip_bfloat16*)(ws + (1u << 20));           // 1 MB
    float* diag    = (float*)(ws + (2u << 20));                          // 32 KB
    float* rowPart = (float*)(ws + (2u << 20) + (1u << 16));             // 2 MB
    float* colPart = (float*)(ws + (4u << 20) + (1u << 16));             // 4 MB

    norm_kernel<<<NB / 4, 256, 0, stream>>>(img, txt, imgB, txtB, diag, (float*)d_out);
    score_kernel<<<2048, 256, 0, stream>>>(imgB, txtB, rowPart, colPart);
    finish_kernel<<<NB / 256, 256, 0, stream>>>(rowPart, colPart, diag, (float*)d_out);
}

// Round 7
// 103.852 us; speedup vs baseline: 1.4742x; 1.0212x over previous
//
#include <hip/hip_runtime.h>
#include <hip/hip_bf16.h>

// ---------------------------------------------------------------------------
// ContrastiveLoss: B=8192, D=64, fp32 inputs, scalar fp32 output.
// Three kernels (R5: contended atomics fusion +55us -> unique-writer partials;
// R4: cooperative launch breaks graph capture).
//   1) norm: fused |x|^2,|t|^2,x.t butterfly per row; bf16 copies (imgB
//      pre-scaled by K1 = LOG2E/T); exact fp32 diagonal; zero d_out.
//   2) score: R7 restructure -- R5/R6 counters showed all pipes <10% busy
//      (load-latency bound on per-wave global B reads). Now each block's 4
//      waves SHARE one 128-col chunk staged once into LDS (16 KB, XOR-swizzled
//      16B quanta for even bank spread); waves differ by strip. ds_read
//      (~120cyc) replaces global (~200-600cyc) in the tile loop.
//   3) finish: reduce 64 row- + 128 col-partials -> logsumexp -> focal loss.
// No max pass needed: unit vectors => |s| <= 1/T; fixed shift M = 1/T keeps
// exp(s-M) in [e^-28.6, 1] (fp32-safe).
// ---------------------------------------------------------------------------

#define NB 8192
#define ND 64

constexpr float INV_T = 1.0f / 0.07f;                 // 14.2857...
constexpr float LOG2E = 1.4426950408889634f;
constexpr float LN2   = 0.6931471805599453f;
constexpr float K1    = INV_T * LOG2E;                // exp2 arg scale

typedef float  floatx4 __attribute__((ext_vector_type(4)));
typedef short  bf16x8  __attribute__((ext_vector_type(8)));

// --------------------------- kernel 1: normalize ---------------------------
// One wave per row (D=64 == wave width). Single fused butterfly reduces
// |x|^2, |t|^2, x.t together. imgB gets the K1-prescaled bf16 copy (A side),
// txtB the plain normalized bf16 (B side). Exact fp32 diagonal to diag.
// Also zeroes d_out (kernel boundary orders it before finish's atomicAdd).
__global__ __launch_bounds__(256)
void norm_kernel(const float* __restrict__ img, const float* __restrict__ txt,
                 __hip_bfloat16* __restrict__ imgB,
                 __hip_bfloat16* __restrict__ txtB,
                 float* __restrict__ diag,
                 float* __restrict__ out)
{
    if (blockIdx.x == 0 && threadIdx.x == 0) out[0] = 0.f;
    const int lane = threadIdx.x & 63;
    const int row  = blockIdx.x * 4 + (threadIdx.x >> 6);
    const float x = img[row * ND + lane];
    const float t = txt[row * ND + lane];
    float sx = x * x, st = t * t, sxt = x * t;
    #pragma unroll
    for (int o = 1; o < 64; o <<= 1) {
        sx  += __shfl_xor(sx,  o, 64);
        st  += __shfl_xor(st,  o, 64);
        sxt += __shfl_xor(sxt, o, 64);
    }
    const float nx_den = fmaxf(sqrtf(sx), 1e-12f);
    const float nt_den = fmaxf(sqrtf(st), 1e-12f);
    imgB[row * ND + lane] = __float2bfloat16(x / nx_den * K1);  // A pre-scaled
    txtB[row * ND + lane] = __float2bfloat16(t / nt_den);
    if (lane == 0) diag[row] = sxt / (nx_den * nt_den) * INV_T;
}

// ----------------------- kernel 2: streamed score pass ---------------------
// 2048 blocks: chunk = blockIdx&63 (128 cols, shared by the block's 4 waves,
// staged in LDS), sgrp = blockIdx>>6; wave wid handles strip sgrp*4+wid
// (64 rows; A-fragments in registers). 8 tiles of 16 cols per wave.
// LDS layout: col c's 128 B stored as 8 16-B quanta at c*128 + (j^(c&7))*16
// (XOR swizzle -> ds_read_b128 spreads evenly over banks; per-tile read addr
// is base + t*2048, an immediate offset).
// mfma_f32_16x16x32_bf16 layouts (HW-verified):
//   A: lane holds A[m=lane&15][k=(lane>>4)*8 + j], j=0..7  (8 contig bf16)
//   B: lane holds B[n=lane&15][k=(lane>>4)*8 + j]          (NT layout)
//   C/D: col = lane&15, row = (lane>>4)*4 + r
__global__ __launch_bounds__(256)
void score_kernel(const __hip_bfloat16* __restrict__ imgB,
                  const __hip_bfloat16* __restrict__ txtB,
                  float* __restrict__ rowPart,   // [64][8192]
                  float* __restrict__ colPart)   // [128][8192]
{
    const int tid   = threadIdx.x;
    const int wid   = tid >> 6;
    const int lane  = tid & 63;
    const int chunk = blockIdx.x & 63;        // cols chunk*128..+127
    const int sgrp  = blockIdx.x >> 6;        // 0..31
    const int strip = sgrp * 4 + wid;         // rows strip*64..+63
    const int m = lane & 15;
    const int q = lane >> 4;

    __shared__ __align__(16) char ldsB[128 * 128];   // 16 KB

    // ---- cooperative stage: txtB chunk (16 KB) -> LDS, XOR-swizzled ----
    {
        const char* src = (const char*)txtB + (size_t)chunk * 16384;
        #pragma unroll
        for (int i = 0; i < 4; ++i) {
            const int idx = i * 256 + tid;    // 16-B quantum id, 0..1023
            const int col = idx >> 3;
            const int j   = idx & 7;
            const float4 v = *(const float4*)(src + idx * 16);
            *(float4*)(ldsB + col * 128 + ((j ^ (col & 7)) << 4)) = v;
        }
    }

    // ---- A fragments: 4 row-tiles of this wave's strip (registers) ----
    const bf16x8* __restrict__ A = (const bf16x8*)imgB;
    const int rowbase = strip * 64;
    bf16x8 a[4][2];
    #pragma unroll
    for (int it = 0; it < 4; ++it) {
        const int r = rowbase + it * 16 + m;
        a[it][0] = A[r * 8 + q];        // k = q*8 .. q*8+7
        a[it][1] = A[r * 8 + 4 + q];    // k = 32 + q*8 ..
    }

    __syncthreads();

    // per-lane LDS b128 bases: col m of tile t lives at t*2048 + m*128;
    // b0 is quantum j=q, b1 quantum j=4+q, both XOR-swizzled by m&7
    const int base0 = m * 128 + (((q    ) ^ (m & 7)) << 4);
    const int base1 = m * 128 + (((4 + q) ^ (m & 7)) << 4);

    float rs[16];
    #pragma unroll
    for (int i = 0; i < 16; ++i) rs[i] = 0.f;

    const floatx4 NEGK = {-K1, -K1, -K1, -K1};   // bakes the -M shift in

    bf16x8 b0 = *(const bf16x8*)(ldsB + base0);
    bf16x8 b1 = *(const bf16x8*)(ldsB + base1);

    #pragma unroll
    for (int t = 0; t < 8; ++t) {
        // prefetch next tile's B from LDS (t=7 wraps: harmless)
        const int tn = (t + 1) & 7;
        const bf16x8 pb0 = *(const bf16x8*)(ldsB + tn * 2048 + base0);
        const bf16x8 pb1 = *(const bf16x8*)(ldsB + tn * 2048 + base1);

        float csp[4];
        #pragma unroll
        for (int it = 0; it < 4; ++it) {
            floatx4 z   = __builtin_amdgcn_mfma_f32_16x16x32_bf16(a[it][0], b0, NEGK, 0, 0, 0);
            floatx4 acc = __builtin_amdgcn_mfma_f32_16x16x32_bf16(a[it][1], b1, z,    0, 0, 0);
            // acc == (s - M) * log2(e) already
            const float e0 = __builtin_amdgcn_exp2f(acc[0]);
            const float e1 = __builtin_amdgcn_exp2f(acc[1]);
            const float e2 = __builtin_amdgcn_exp2f(acc[2]);
            const float e3 = __builtin_amdgcn_exp2f(acc[3]);
            rs[it * 4 + 0] += e0;
            rs[it * 4 + 1] += e1;
            rs[it * 4 + 2] += e2;
            rs[it * 4 + 3] += e3;
            csp[it] = (e0 + e1) + (e2 + e3);     // depth-2 tree
        }
        float cs = (csp[0] + csp[1]) + (csp[2] + csp[3]);
        // combine the 4 quads -> col sum over all 64 rows of the strip
        cs += __shfl_xor(cs, 16, 64);
        cs += __shfl_xor(cs, 32, 64);
        if (q == 0) colPart[strip * NB + chunk * 128 + (t << 4) + m] = cs;  // unique writer
        b0 = pb0; b1 = pb1;
    }

    // flush row sums: reduce each rs[idx] across the 16 lanes of the quad
    #pragma unroll
    for (int idx = 0; idx < 16; ++idx) {
        float v = rs[idx];
        v += __shfl_xor(v, 1, 64);
        v += __shfl_xor(v, 2, 64);
        v += __shfl_xor(v, 4, 64);
        v += __shfl_xor(v, 8, 64);
        if (m == idx) {
            const int it = idx >> 2, r = idx & 3;
            rowPart[chunk * NB + rowbase + it * 16 + q * 4 + r] = v;  // unique writer
        }
    }
}

// --------------------------- kernel 3: finish ------------------------------
__global__ __launch_bounds__(256)
void finish_kernel(const float* __restrict__ rowPart,
                   const float* __restrict__ colPart,
                   const float* __restrict__ diag,
                   float* __restrict__ out)
{
    const int i = blockIdx.x * 256 + threadIdx.x;   // 0..8191
    float rowS = 0.f, colS = 0.f;
    #pragma unroll 4
    for (int c = 0; c < 64; ++c)  rowS += rowPart[c * NB + i];
    #pragma unroll 4
    for (int s = 0; s < 128; ++s) colS += colPart[s * NB + i];
    const float d     = diag[i];
    const float lse_r = INV_T + __builtin_amdgcn_logf(rowS) * LN2;
    const float lse_c = INV_T + __builtin_amdgcn_logf(colS) * LN2;
    const float lpr = d - lse_r;
    const float lpc = d - lse_c;
    const float p   = __builtin_amdgcn_exp2f(lpr * LOG2E);
    const float om  = 1.f - p;
    float contrib = om * om * (-lpr - lpc) * (0.5f / (float)NB);

    #pragma unroll
    for (int o = 1; o < 64; o <<= 1) contrib += __shfl_xor(contrib, o, 64);
    __shared__ float red[4];
    if ((threadIdx.x & 63) == 0) red[threadIdx.x >> 6] = contrib;
    __syncthreads();
    if (threadIdx.x == 0)
        atomicAdd(out, red[0] + red[1] + red[2] + red[3]);
}

// ---------------------------------------------------------------------------
extern "C" void kernel_launch(void* const* d_in, const int* in_sizes, int n_in,
                              void* d_out, int out_size, void* d_ws, size_t ws_size,
                              hipStream_t stream)
{
    const float* img = (const float*)d_in[0];
    const float* txt = (const float*)d_in[1];

    char* ws = (char*)d_ws;
    __hip_bfloat16* imgB = (__hip_bfloat16*)(ws);                        // 1 MB
    __hip_bfloat16* txtB = (__hip_bfloat16*)(ws + (1u << 20));           // 1 MB
    float* diag    = (float*)(ws + (2u << 20));                          // 32 KB
    float* rowPart = (float*)(ws + (2u << 20) + (1u << 16));             // 2 MB
    float* colPart = (float*)(ws + (4u << 20) + (1u << 16));             // 4 MB

    norm_kernel<<<NB / 4, 256, 0, stream>>>(img, txt, imgB, txtB, diag, (float*)d_out);
    score_kernel<<<2048, 256, 0, stream>>>(imgB, txtB, rowPart, colPart);
    finish_kernel<<<NB / 256, 256, 0, stream>>>(rowPart, colPart, diag, (float*)d_out);
}